// Round 16
// baseline (310.944 us; speedup 1.0000x reference)
//
#include <hip/hip_runtime.h>
#include <hip/hip_bf16.h>
#include <hip/hip_fp16.h>

// Problem constants: N=100000, D_IN=256, C=4, D_C=32, E=1.6e6
#define D_IN 256
#define D_OUT 128   // C * D_C
#define D_C 32
#define NUM_C 4
#define RB_LOG 10
#define RB 1024         // rows per bucket
#define MB_MAX 400      // bucket-array capacity (NUM_C * ceil(N/RB) = 392)
#define RSTASH 24       // rowsort key stash (24*1024 covers typical span ~23k)

typedef _Float16 f16x8 __attribute__((ext_vector_type(8)));
typedef float    f32x4 __attribute__((ext_vector_type(4)));

// ---- W convert+transpose: W[256][128] fp32 -> Wt[128][256] fp16 ----------
__global__ void wcvt_kernel(const float* __restrict__ W, __half* __restrict__ Wt) {
    int t = blockIdx.x * 256 + threadIdx.x;   // 0 .. 32767
    if (t >= D_IN * D_OUT) return;
    int col = t >> 8;     // 0..127
    int k   = t & 255;    // 0..255
    Wt[col * D_IN + k] = __float2half(W[k * D_OUT + col]);
}

// ---- bucket histogram (standalone, LDS-aggregated, int4 loads) -----------
__global__ __launch_bounds__(256) void bucket_hist_kernel(const int* __restrict__ rows,
                                                          int* __restrict__ bcnt,
                                                          int CE, int E, int NB, int MB) {
    __shared__ int h[MB_MAX];
    const int t = threadIdx.x;
    for (int i = t; i < MB; i += 256) h[i] = 0;
    __syncthreads();
    const int CE4 = CE >> 2;
    const int4* rows4 = reinterpret_cast<const int4*>(rows);
    int base4 = blockIdx.x * 4096;
    #pragma unroll 4
    for (int i = 0; i < 16; ++i) {
        int i4 = base4 + t + i * 256;
        if (i4 < CE4) {
            int e0 = i4 << 2;
            int c = (e0 >= 3 * E) ? 3 : (e0 >= 2 * E) ? 2 : (e0 >= E) ? 1 : 0;
            int4 rv = rows4[i4];
            atomicAdd(&h[c * NB + (rv.x >> RB_LOG)], 1);
            atomicAdd(&h[c * NB + (rv.y >> RB_LOG)], 1);
            atomicAdd(&h[c * NB + (rv.z >> RB_LOG)], 1);
            atomicAdd(&h[c * NB + (rv.w >> RB_LOG)], 1);
        }
    }
    if (blockIdx.x == 0 && t < (CE & 3)) {
        int e = (CE4 << 2) + t;
        int c = (e >= 3 * E) ? 3 : (e >= 2 * E) ? 2 : (e >= E) ? 1 : 0;
        atomicAdd(&h[c * NB + (rows[e] >> RB_LOG)], 1);
    }
    __syncthreads();
    for (int i = t; i < MB; i += 256)
        if (h[i]) atomicAdd(&bcnt[i], h[i]);
}

// ---- scan: padded (16-record units) + dense offsets ----------------------
__global__ __launch_bounds__(512) void bucket_scan_kernel(const int* __restrict__ bcnt,
                                                          int* __restrict__ bstartU,
                                                          int* __restrict__ bheadU,
                                                          int* __restrict__ bstartD,
                                                          int* __restrict__ starts,
                                                          int MB, int M, int slackUnits) {
    __shared__ int sd[512];
    int t = threadIdx.x;
    int v = (t < MB) ? bcnt[t] : 0;
    int capU = ((v + 15) >> 4) + slackUnits;
    sd[t] = capU; __syncthreads();
    for (int off = 1; off < 512; off <<= 1) {
        int add = (t >= off) ? sd[t - off] : 0;
        __syncthreads();
        sd[t] += add;
        __syncthreads();
    }
    int exclU = sd[t] - capU;
    if (t < MB) { bstartU[t] = exclU; bheadU[t] = exclU; }
    __syncthreads();
    sd[t] = v; __syncthreads();
    for (int off = 1; off < 512; off <<= 1) {
        int add = (t >= off) ? sd[t - off] : 0;
        __syncthreads();
        sd[t] += add;
        __syncthreads();
    }
    int exclD = sd[t] - v;
    if (t < MB) bstartD[t] = exclD;
    if (t == 511) starts[M] = sd[511];   // sentinel = total edges
}

// ---- fused: partition (SoA, unit-16 aligned) + MFMA GEMM (128-row) -------
// blockIdx < partBlocks: two-pass partition: rec[pos]=fp16(val)<<17|col, rl[pos]=rowlocal
// else: tmp[c][N][32] fp16 = x @ W ; 128 rows/block, 8 waves = (rowhalf, cls)
__global__ __launch_bounds__(512) void part_gemm_kernel(const int* __restrict__ rows,
                                                        const int* __restrict__ cols,
                                                        const float* __restrict__ vals,
                                                        int* __restrict__ bheadU,
                                                        unsigned* __restrict__ rec,
                                                        unsigned short* __restrict__ rl,
                                                        int CE, int E, int NB, int MB,
                                                        int partBlocks,
                                                        const float* __restrict__ x,
                                                        const __half* __restrict__ Wt,
                                                        __half* __restrict__ tmp,
                                                        int Nrows) {
    __shared__ __align__(16) char smem[65536];   // union: As (64KB) | lcnt+lbase
    const int t = threadIdx.x;

    if (blockIdx.x < partBlocks) {
        int* lcnt  = (int*)smem;
        int* lbase = lcnt + MB_MAX;     // absolute RECORD base for this block's run
        for (int i = t; i < MB; i += 512) lcnt[i] = 0;
        __syncthreads();
        const int base = blockIdx.x * 8192;
        const int end  = min(base + 8192, CE);

        // pass 1: count (int4 loads, plain atomics)
        {
            int nvec4 = (end - base) >> 2;
            const int4* rows4 = reinterpret_cast<const int4*>(rows + base);
            #pragma unroll 4
            for (int i = 0; i < 4; ++i) {
                int i4 = t + i * 512;
                if (i4 < nvec4) {
                    int e0 = base + (i4 << 2);
                    int c = (e0 >= 3 * E) ? 3 : (e0 >= 2 * E) ? 2 : (e0 >= E) ? 1 : 0;
                    int4 rv = rows4[i4];
                    atomicAdd(&lcnt[c * NB + (rv.x >> RB_LOG)], 1);
                    atomicAdd(&lcnt[c * NB + (rv.y >> RB_LOG)], 1);
                    atomicAdd(&lcnt[c * NB + (rv.z >> RB_LOG)], 1);
                    atomicAdd(&lcnt[c * NB + (rv.w >> RB_LOG)], 1);
                }
            }
            int e = base + (((end - base) >> 2) << 2) + t;
            if (e < end) {
                int c = (e >= 3 * E) ? 3 : (e >= 2 * E) ? 2 : (e >= E) ? 1 : 0;
                atomicAdd(&lcnt[c * NB + (rows[e] >> RB_LOG)], 1);
            }
        }
        __syncthreads();

        // reserve unit-aligned runs (unit = 16 records)
        for (int b = t; b < MB; b += 512) {
            int n = lcnt[b];
            lbase[b] = n ? atomicAdd(&bheadU[b], (n + 15) >> 4) * 16 : 0;
        }
        __syncthreads();
        for (int i = t; i < MB; i += 512) lcnt[i] = 0;   // reuse as rank counters
        __syncthreads();

        // pass 2: rank + write final-format record + sort key
        for (int i = 0; i < 16; ++i) {
            int e = base + t + i * 512;
            if (e < end) {
                int c = (e >= 3 * E) ? 3 : (e >= 2 * E) ? 2 : (e >= E) ? 1 : 0;
                int r = rows[e];
                int b = c * NB + (r >> RB_LOG);
                int rank = atomicAdd(&lcnt[b], 1);
                int pos = lbase[b] + rank;
                __half h = __float2half(vals[e]);
                unsigned hb = (unsigned)*reinterpret_cast<unsigned short*>(&h);
                rec[pos] = (hb << 17) | (unsigned)cols[e];
                rl[pos]  = (unsigned short)(r & (RB - 1));
            }
        }
        __syncthreads();

        // pad fill: only the key array needs markers (rec pads never read)
        for (int b = t; b < MB; b += 512) {
            int n = lcnt[b];
            if (n) {
                int endp = ((n + 15) >> 4) << 4;
                for (int s2 = n; s2 < endp; ++s2)
                    rl[lbase[b] + s2] = 0xFFFFu;
            }
        }
    } else {
        f16x8* As = (f16x8*)smem;   // 128 rows x 32 kc, swizzled
        const int brow = (blockIdx.x - partBlocks) * 128;
        const int w   = t >> 6;      // wave 0..7
        const int cls = w & 3;       // class
        const int rh  = w >> 2;      // row half: 0..1
        const int l   = t & 63;
        const int l15 = l & 15;
        const int hi  = l >> 4;      // 0..3

        // preload this wave's 16 B-fragments (class cls)
        f16x8 bf[8][2];
        #pragma unroll
        for (int ks = 0; ks < 8; ++ks)
            #pragma unroll
            for (int cti = 0; cti < 2; ++cti)
                bf[ks][cti] = *reinterpret_cast<const f16x8*>(
                    Wt + (size_t)((cls * 2 + cti) * 16 + l15) * D_IN + ks * 32 + hi * 8);

        // stage 128-row x-tile -> fp16 LDS
        #pragma unroll
        for (int i = 0; i < 8; ++i) {
            int ci  = i * 512 + t;     // 0..4095
            int row = ci >> 5;         // 0..127
            int kc  = ci & 31;
            int grow = brow + row;
            float4 a0 = make_float4(0.f, 0.f, 0.f, 0.f);
            float4 a1 = make_float4(0.f, 0.f, 0.f, 0.f);
            if (grow < Nrows) {
                const float* src = x + (size_t)grow * D_IN + kc * 8;
                a0 = *reinterpret_cast<const float4*>(src);
                a1 = *reinterpret_cast<const float4*>(src + 4);
            }
            f16x8 hh;
            hh[0] = (_Float16)a0.x; hh[1] = (_Float16)a0.y;
            hh[2] = (_Float16)a0.z; hh[3] = (_Float16)a0.w;
            hh[4] = (_Float16)a1.x; hh[5] = (_Float16)a1.y;
            hh[6] = (_Float16)a1.z; hh[7] = (_Float16)a1.w;
            As[kc * 128 + (row ^ kc)] = hh;
        }
        __syncthreads();

        f32x4 acc[4][2] = {};
        #pragma unroll
        for (int rt = 0; rt < 4; ++rt) {
            const int arow = rh * 64 + rt * 16 + l15;
            #pragma unroll
            for (int ks = 0; ks < 8; ++ks) {
                const int kcA = ks * 4 + hi;
                f16x8 afrag = As[kcA * 128 + (arow ^ kcA)];
                acc[rt][0] = __builtin_amdgcn_mfma_f32_16x16x32_f16(afrag, bf[ks][0], acc[rt][0], 0, 0, 0);
                acc[rt][1] = __builtin_amdgcn_mfma_f32_16x16x32_f16(afrag, bf[ks][1], acc[rt][1], 0, 0, 0);
            }
        }

        #pragma unroll
        for (int rt = 0; rt < 4; ++rt)
            #pragma unroll
            for (int cti = 0; cti < 2; ++cti) {
                const int cio = cti * 16 + l15;
                #pragma unroll
                for (int r = 0; r < 4; ++r) {
                    int grow = brow + rh * 64 + rt * 16 + hi * 4 + r;
                    if (grow < Nrows)
                        tmp[((size_t)cls * Nrows + grow) * 32 + cio] = __float2half((float)acc[rt][cti][r]);
                }
            }
    }
}

// ---- rowsort: SoA two-pass counting sort; key stash in registers ---------
__global__ __launch_bounds__(1024) void rowsort_kernel(const int* __restrict__ bstartU,
                                                       const int* __restrict__ bheadU,
                                                       const int* __restrict__ bstartD,
                                                       const unsigned short* __restrict__ rl,
                                                       const unsigned* __restrict__ rec,
                                                       unsigned* __restrict__ dst,
                                                       int* __restrict__ starts,
                                                       int N, int NB) {
    __shared__ int lcnt[RB];   // 1024 bins
    __shared__ int sd[RB];
    int b = blockIdx.x;
    int c = b / NB, rb = b - c * NB;
    int t = threadIdx.x;
    int s = bstartU[b] * 16;
    int span = bheadU[b] * 16 - s;
    int dbase = bstartD[b];

    unsigned short st[RSTASH];
    lcnt[t] = 0;
    __syncthreads();
    #pragma unroll
    for (int k = 0; k < RSTASH; ++k) {
        int i = t + k * 1024;
        if (i < span) {
            unsigned short r = rl[s + i];
            st[k] = r;
            if (r < RB) atomicAdd(&lcnt[r], 1);
        }
    }
    for (int i = t + RSTASH * 1024; i < span; i += 1024) {
        unsigned short r = rl[s + i];
        if (r < RB) atomicAdd(&lcnt[r], 1);
    }
    __syncthreads();
    int v = lcnt[t];
    sd[t] = v; __syncthreads();
    for (int off = 1; off < 1024; off <<= 1) {
        int add = (t >= off) ? sd[t - off] : 0;
        __syncthreads();
        sd[t] += add;
        __syncthreads();
    }
    int excl = sd[t] - v;
    int grow = (rb << RB_LOG) + t;
    if (grow < N) starts[c * N + grow] = dbase + excl;
    __syncthreads();
    lcnt[t] = excl;
    __syncthreads();
    #pragma unroll
    for (int k = 0; k < RSTASH; ++k) {
        int i = t + k * 1024;
        if (i < span) {
            unsigned short r = st[k];
            if (r < RB) {
                int pos = atomicAdd(&lcnt[r], 1);
                dst[dbase + pos] = rec[s + i];
            }
        }
    }
    for (int i = t + RSTASH * 1024; i < span; i += 1024) {
        unsigned short r = rl[s + i];
        if (r < RB) {
            int pos = atomicAdd(&lcnt[r], 1);
            dst[dbase + pos] = rec[s + i];
        }
    }
}

// ---- pull: 8-lane group per (class,row); uint2 (4xfp16) gather; ReLU -----
__global__ __launch_bounds__(256) void pull2_kernel(const int* __restrict__ starts,
                                                    const unsigned* __restrict__ arena,
                                                    const uint2* __restrict__ tmp4,
                                                    float* __restrict__ out,
                                                    int N, int M) {
    int p = blockIdx.x * 32 + (threadIdx.x >> 3);
    if (p >= M) return;
    const int lf = threadIdx.x & 7;   // feature quad: [lf*4, lf*4+4)
    int c   = p / N;
    int row = p - c * N;
    int s = starts[p];
    int n = starts[p + 1] - s;
    const uint2* tc = tmp4 + (size_t)c * N * 8 + lf;   // row stride 8 uint2

    float4 acc = make_float4(0.f, 0.f, 0.f, 0.f);
    int base = 0;
    for (; base + 16 <= n; base += 16) {
        unsigned r[16];
        #pragma unroll
        for (int j = 0; j < 16; ++j) r[j] = arena[s + base + j];
        #pragma unroll
        for (int j = 0; j < 16; ++j) {
            unsigned short hb = (unsigned short)(r[j] >> 17);
            float v = __half2float(*reinterpret_cast<__half*>(&hb));
            uint2 tw = tc[(size_t)(r[j] & 0x1FFFFu) * 8];
            float2 t0 = __half22float2(*reinterpret_cast<__half2*>(&tw.x));
            float2 t1 = __half22float2(*reinterpret_cast<__half2*>(&tw.y));
            acc.x = fmaf(v, t0.x, acc.x);
            acc.y = fmaf(v, t0.y, acc.y);
            acc.z = fmaf(v, t1.x, acc.z);
            acc.w = fmaf(v, t1.y, acc.w);
        }
    }
    if (base + 8 <= n) {
        unsigned r[8];
        #pragma unroll
        for (int j = 0; j < 8; ++j) r[j] = arena[s + base + j];
        #pragma unroll
        for (int j = 0; j < 8; ++j) {
            unsigned short hb = (unsigned short)(r[j] >> 17);
            float v = __half2float(*reinterpret_cast<__half*>(&hb));
            uint2 tw = tc[(size_t)(r[j] & 0x1FFFFu) * 8];
            float2 t0 = __half22float2(*reinterpret_cast<__half2*>(&tw.x));
            float2 t1 = __half22float2(*reinterpret_cast<__half2*>(&tw.y));
            acc.x = fmaf(v, t0.x, acc.x);
            acc.y = fmaf(v, t0.y, acc.y);
            acc.z = fmaf(v, t1.x, acc.z);
            acc.w = fmaf(v, t1.y, acc.w);
        }
        base += 8;
    }
    for (; base < n; ++base) {
        unsigned u = arena[s + base];
        unsigned short hb = (unsigned short)(u >> 17);
        float v = __half2float(*reinterpret_cast<__half*>(&hb));
        uint2 tw = tc[(size_t)(u & 0x1FFFFu) * 8];
        float2 t0 = __half22float2(*reinterpret_cast<__half2*>(&tw.x));
        float2 t1 = __half22float2(*reinterpret_cast<__half2*>(&tw.y));
        acc.x = fmaf(v, t0.x, acc.x);
        acc.y = fmaf(v, t0.y, acc.y);
        acc.z = fmaf(v, t1.x, acc.z);
        acc.w = fmaf(v, t1.y, acc.w);
    }
    *reinterpret_cast<float4*>(&out[(size_t)row * D_OUT + c * D_C + 4 * lf]) =
        make_float4(fmaxf(acc.x, 0.f), fmaxf(acc.y, 0.f),
                    fmaxf(acc.z, 0.f), fmaxf(acc.w, 0.f));
}

// ---- fallback: atomic push + relu ----------------------------------------
__global__ __launch_bounds__(256) void scatter_kernel(const int* __restrict__ rows,
                                                      const int* __restrict__ cols,
                                                      const float* __restrict__ vals,
                                                      const __half* __restrict__ tmp,
                                                      float* __restrict__ out,
                                                      long long totalEdges, int E, int N) {
    long long gid = (long long)blockIdx.x * 8 + (threadIdx.x >> 5);
    if (gid >= totalEdges) return;
    const int lane = threadIdx.x & 31;
    const long long e1 = E, e2 = 2LL * E, e3 = 3LL * E;
    int c = (gid >= e3) ? 3 : (gid >= e2) ? 2 : (gid >= e1) ? 1 : 0;
    const float tv = __half2float(tmp[((size_t)c * N + cols[gid]) * 32 + lane]);
    atomicAdd(&out[(size_t)rows[gid] * D_OUT + c * D_C + lane], tv * vals[gid]);
}

__global__ void relu_kernel(float* __restrict__ out, int n4) {
    int i = blockIdx.x * blockDim.x + threadIdx.x;
    if (i < n4) {
        float4 v = reinterpret_cast<float4*>(out)[i];
        v.x = fmaxf(v.x, 0.f); v.y = fmaxf(v.y, 0.f);
        v.z = fmaxf(v.z, 0.f); v.w = fmaxf(v.w, 0.f);
        reinterpret_cast<float4*>(out)[i] = v;
    }
}

extern "C" void kernel_launch(void* const* d_in, const int* in_sizes, int n_in,
                              void* d_out, int out_size, void* d_ws, size_t ws_size,
                              hipStream_t stream) {
    const float* x    = (const float*)d_in[0];
    const float* W    = (const float*)d_in[1];
    const int*   rows = (const int*)d_in[2];
    const int*   cols = (const int*)d_in[3];
    const float* vals = (const float*)d_in[4];
    float* out = (float*)d_out;

    const int N  = in_sizes[0] / D_IN;      // 100000
    const int CE = in_sizes[2];             // 6,400,000
    const int E  = CE / NUM_C;
    const int NB = (N + RB - 1) >> RB_LOG;  // 98
    const int MB = NUM_C * NB;              // 392
    const int M  = NUM_C * N;               // 400,000

    const int partBlocks = (CE + 8191) / 8192;            // 782
    const int gemmBlocks = (N + 127) / 128;               // 782
    const int slackUnits = (15 * partBlocks + 15) / 16 + 1;
    const long long capRecs = (long long)((CE + 15) & ~15)
                            + (long long)MB * slackUnits * 16 + (long long)MB * 16;

    // workspace layout
    size_t off = 0;
    __half* tmp  = (__half*)((char*)d_ws + off); off += (size_t)N * D_OUT * 2;
    off = (off + 15) & ~(size_t)15;
    __half* Wt   = (__half*)((char*)d_ws + off); off += (size_t)D_IN * D_OUT * 2;
    int* bcnt    = (int*)((char*)d_ws + off);   off += (size_t)MB * 4;
    int* bstartU = (int*)((char*)d_ws + off);   off += (size_t)MB * 4;
    int* bheadU  = (int*)((char*)d_ws + off);   off += (size_t)MB * 4;
    int* bstartD = (int*)((char*)d_ws + off);   off += (size_t)MB * 4;
    int* starts  = (int*)((char*)d_ws + off);   off += (size_t)(M + 1) * 4;
    off = (off + 63) & ~(size_t)63;             // line-align arrays
    unsigned* rec = (unsigned*)((char*)d_ws + off);        off += (size_t)capRecs * 4;
    off = (off + 63) & ~(size_t)63;
    unsigned short* rlA = (unsigned short*)((char*)d_ws + off); off += (size_t)capRecs * 2;
    off = (off + 63) & ~(size_t)63;
    unsigned* sorted = (unsigned*)((char*)d_ws + off);     off += (size_t)CE * 4;
    const bool ok = (off <= ws_size) && (MB <= MB_MAX) && (MB <= 512);

    wcvt_kernel<<<(D_IN * D_OUT + 255) / 256, 256, 0, stream>>>(W, Wt);

    if (ok) {
        hipMemsetAsync(bcnt, 0, (size_t)MB * 4, stream);
        const int histBlocks = ((CE >> 2) + 4095) / 4096;
        bucket_hist_kernel<<<histBlocks, 256, 0, stream>>>(rows, bcnt, CE, E, NB, MB);
        bucket_scan_kernel<<<1, 512, 0, stream>>>(bcnt, bstartU, bheadU, bstartD, starts, MB, M, slackUnits);
        part_gemm_kernel<<<partBlocks + gemmBlocks, 512, 0, stream>>>(
            rows, cols, vals, bheadU, rec, rlA, CE, E, NB, MB, partBlocks, x, Wt, tmp, N);
        rowsort_kernel<<<MB, 1024, 0, stream>>>(bstartU, bheadU, bstartD, rlA, rec, sorted, starts, N, NB);
        const int pullBlocks = (M + 31) / 32;
        pull2_kernel<<<pullBlocks, 256, 0, stream>>>(starts, sorted,
                                                     reinterpret_cast<const uint2*>(tmp), out, N, M);
    } else {
        // pure-gemm launch (partBlocks=0 -> bid = gemm idx), then atomic fallback
        part_gemm_kernel<<<gemmBlocks, 512, 0, stream>>>(
            rows, cols, vals, bheadU, rec, rlA, CE, E, NB, MB, 0, x, Wt, tmp, N);
        hipMemsetAsync(d_out, 0, (size_t)out_size * sizeof(float), stream);
        const int scatterBlocks = (CE + 7) / 8;
        scatter_kernel<<<scatterBlocks, 256, 0, stream>>>(rows, cols, vals, tmp, out, (long long)CE, E, N);
        const int n4 = out_size / 4;
        relu_kernel<<<(n4 + 255) / 256, 256, 0, stream>>>(out, n4);
    }
}

// Round 17
// 295.084 us; speedup vs baseline: 1.0537x; 1.0537x over previous
//
#include <hip/hip_runtime.h>
#include <hip/hip_bf16.h>
#include <hip/hip_fp16.h>

// Problem constants: N=100000, D_IN=256, C=4, D_C=32, E=1.6e6
#define D_IN 256
#define D_OUT 128   // C * D_C
#define D_C 32
#define NUM_C 4
#define RB_LOG 10
#define RB 1024         // rows per bucket
#define MB_MAX 400      // bucket-array capacity (NUM_C * ceil(N/RB) = 392)
#define PART_E 16384    // edges per partition block

typedef _Float16 f16x8 __attribute__((ext_vector_type(8)));
typedef float    f32x4 __attribute__((ext_vector_type(4)));

// ---- W convert+transpose: W[256][128] fp32 -> Wt[128][256] fp16 ----------
__global__ void wcvt_kernel(const float* __restrict__ W, __half* __restrict__ Wt) {
    int t = blockIdx.x * 256 + threadIdx.x;   // 0 .. 32767
    if (t >= D_IN * D_OUT) return;
    int col = t >> 8;     // 0..127
    int k   = t & 255;    // 0..255
    Wt[col * D_IN + k] = __float2half(W[k * D_OUT + col]);
}

// ---- bucket histogram (standalone, LDS-aggregated, int4 loads) -----------
__global__ __launch_bounds__(256) void bucket_hist_kernel(const int* __restrict__ rows,
                                                          int* __restrict__ bcnt,
                                                          int CE, int E, int NB, int MB) {
    __shared__ int h[MB_MAX];
    const int t = threadIdx.x;
    for (int i = t; i < MB; i += 256) h[i] = 0;
    __syncthreads();
    const int CE4 = CE >> 2;
    const int4* rows4 = reinterpret_cast<const int4*>(rows);
    int base4 = blockIdx.x * 4096;
    #pragma unroll 4
    for (int i = 0; i < 16; ++i) {
        int i4 = base4 + t + i * 256;
        if (i4 < CE4) {
            int e0 = i4 << 2;
            int c = (e0 >= 3 * E) ? 3 : (e0 >= 2 * E) ? 2 : (e0 >= E) ? 1 : 0;
            int4 rv = rows4[i4];
            atomicAdd(&h[c * NB + (rv.x >> RB_LOG)], 1);
            atomicAdd(&h[c * NB + (rv.y >> RB_LOG)], 1);
            atomicAdd(&h[c * NB + (rv.z >> RB_LOG)], 1);
            atomicAdd(&h[c * NB + (rv.w >> RB_LOG)], 1);
        }
    }
    if (blockIdx.x == 0 && t < (CE & 3)) {
        int e = (CE4 << 2) + t;
        int c = (e >= 3 * E) ? 3 : (e >= 2 * E) ? 2 : (e >= E) ? 1 : 0;
        atomicAdd(&h[c * NB + (rows[e] >> RB_LOG)], 1);
    }
    __syncthreads();
    for (int i = t; i < MB; i += 256)
        if (h[i]) atomicAdd(&bcnt[i], h[i]);
}

// ---- scan: padded (line-aligned) + dense offsets -------------------------
__global__ __launch_bounds__(512) void bucket_scan_kernel(const int* __restrict__ bcnt,
                                                          int* __restrict__ bstartP,
                                                          int* __restrict__ bheadLine,
                                                          int* __restrict__ bstartD,
                                                          int* __restrict__ starts,
                                                          int MB, int M, int slackLines) {
    __shared__ int sd[512];
    int t = threadIdx.x;
    int v = (t < MB) ? bcnt[t] : 0;
    int capL = ((v + 7) >> 3) + slackLines;
    sd[t] = capL; __syncthreads();
    for (int off = 1; off < 512; off <<= 1) {
        int add = (t >= off) ? sd[t - off] : 0;
        __syncthreads();
        sd[t] += add;
        __syncthreads();
    }
    int exclL = sd[t] - capL;
    if (t < MB) { bstartP[t] = exclL * 8; bheadLine[t] = exclL; }
    __syncthreads();
    sd[t] = v; __syncthreads();
    for (int off = 1; off < 512; off <<= 1) {
        int add = (t >= off) ? sd[t - off] : 0;
        __syncthreads();
        sd[t] += add;
        __syncthreads();
    }
    int exclD = sd[t] - v;
    if (t < MB) bstartD[t] = exclD;
    if (t == 511) starts[M] = sd[511];   // sentinel = total edges
}

// ---- fused: partition (16384 edges/blk) + MFMA GEMM (128-row, 32KB LDS) --
// blockIdx < partBlocks: two-pass partition into line-aligned AoS arena.
// else: tmp[c][N][32] fp16 = x @ W ; 128 rows/block, K in two 128-halves.
__global__ __launch_bounds__(512) void part_gemm_kernel(const int* __restrict__ rows,
                                                        const int* __restrict__ cols,
                                                        const float* __restrict__ vals,
                                                        int* __restrict__ bheadLine,
                                                        int2* __restrict__ arena,
                                                        int CE, int E, int NB, int MB,
                                                        int partBlocks,
                                                        const float* __restrict__ x,
                                                        const __half* __restrict__ Wt,
                                                        __half* __restrict__ tmp,
                                                        int Nrows) {
    __shared__ __align__(16) char smem[32768];   // union: As (32KB) | lcnt+lbase
    const int t = threadIdx.x;

    if (blockIdx.x < partBlocks) {
        int* lcnt  = (int*)smem;
        int* lbase = lcnt + MB_MAX;     // absolute RECORD base for this block's run
        for (int i = t; i < MB; i += 512) lcnt[i] = 0;
        __syncthreads();
        const int base = blockIdx.x * PART_E;
        const int end  = min(base + PART_E, CE);

        // pass 1: count (int4 loads, plain atomics)
        {
            int nvec4 = (end - base) >> 2;
            const int4* rows4 = reinterpret_cast<const int4*>(rows + base);
            #pragma unroll 4
            for (int i = 0; i < 8; ++i) {
                int i4 = t + i * 512;
                if (i4 < nvec4) {
                    int e0 = base + (i4 << 2);
                    int c = (e0 >= 3 * E) ? 3 : (e0 >= 2 * E) ? 2 : (e0 >= E) ? 1 : 0;
                    int4 rv = rows4[i4];
                    atomicAdd(&lcnt[c * NB + (rv.x >> RB_LOG)], 1);
                    atomicAdd(&lcnt[c * NB + (rv.y >> RB_LOG)], 1);
                    atomicAdd(&lcnt[c * NB + (rv.z >> RB_LOG)], 1);
                    atomicAdd(&lcnt[c * NB + (rv.w >> RB_LOG)], 1);
                }
            }
            int e = base + (((end - base) >> 2) << 2) + t;
            if (e < end) {
                int c = (e >= 3 * E) ? 3 : (e >= 2 * E) ? 2 : (e >= E) ? 1 : 0;
                atomicAdd(&lcnt[c * NB + (rows[e] >> RB_LOG)], 1);
            }
        }
        __syncthreads();

        // reserve line-aligned runs
        for (int b = t; b < MB; b += 512) {
            int n = lcnt[b];
            lbase[b] = n ? atomicAdd(&bheadLine[b], (n + 7) >> 3) * 8 : 0;
        }
        __syncthreads();
        for (int i = t; i < MB; i += 512) lcnt[i] = 0;   // reuse as rank counters
        __syncthreads();

        // pass 2: rank + write
        for (int i = 0; i < 32; ++i) {
            int e = base + t + i * 512;
            if (e < end) {
                int c = (e >= 3 * E) ? 3 : (e >= 2 * E) ? 2 : (e >= E) ? 1 : 0;
                int r = rows[e];
                int b = c * NB + (r >> RB_LOG);
                int rank = atomicAdd(&lcnt[b], 1);
                arena[lbase[b] + rank] = make_int2(cols[e] | ((r & (RB - 1)) << 17),
                                                   __float_as_int(vals[e]));
            }
        }
        __syncthreads();

        // pad fill so every reserved line is fully written
        for (int b = t; b < MB; b += 512) {
            int n = lcnt[b];
            if (n) {
                int endp = ((n + 7) >> 3) * 8;
                for (int s2 = n; s2 < endp; ++s2)
                    arena[lbase[b] + s2] = make_int2(-1, 0);
            }
        }
    } else {
        f16x8* As = (f16x8*)smem;   // 128 rows x 16 kc (one K-half), swizzled
        const int brow = (blockIdx.x - partBlocks) * 128;
        const int w   = t >> 6;      // wave 0..7
        const int cls = w & 3;       // class
        const int rh  = w >> 2;      // row half: 0..1
        const int l   = t & 63;
        const int l15 = l & 15;
        const int hi  = l >> 4;      // 0..3

        // preload this wave's 16 B-fragments (class cls), covering all K
        f16x8 bf[8][2];
        #pragma unroll
        for (int ks = 0; ks < 8; ++ks)
            #pragma unroll
            for (int cti = 0; cti < 2; ++cti)
                bf[ks][cti] = *reinterpret_cast<const f16x8*>(
                    Wt + (size_t)((cls * 2 + cti) * 16 + l15) * D_IN + ks * 32 + hi * 8);

        f32x4 acc[4][2] = {};

        #pragma unroll
        for (int half = 0; half < 2; ++half) {
            // stage 128 rows x 128 k (fp16) for this half
            #pragma unroll
            for (int i = 0; i < 4; ++i) {
                int ci  = i * 512 + t;     // 0..2047
                int row = ci >> 4;         // 0..127
                int kc  = ci & 15;         // 0..15 (8 fp16 each)
                int grow = brow + row;
                float4 a0 = make_float4(0.f, 0.f, 0.f, 0.f);
                float4 a1 = make_float4(0.f, 0.f, 0.f, 0.f);
                if (grow < Nrows) {
                    const float* src = x + (size_t)grow * D_IN + half * 128 + kc * 8;
                    a0 = *reinterpret_cast<const float4*>(src);
                    a1 = *reinterpret_cast<const float4*>(src + 4);
                }
                f16x8 hh;
                hh[0] = (_Float16)a0.x; hh[1] = (_Float16)a0.y;
                hh[2] = (_Float16)a0.z; hh[3] = (_Float16)a0.w;
                hh[4] = (_Float16)a1.x; hh[5] = (_Float16)a1.y;
                hh[6] = (_Float16)a1.z; hh[7] = (_Float16)a1.w;
                As[kc * 128 + (row ^ kc)] = hh;
            }
            __syncthreads();

            #pragma unroll
            for (int rt = 0; rt < 4; ++rt) {
                const int arow = rh * 64 + rt * 16 + l15;
                #pragma unroll
                for (int ks2 = 0; ks2 < 4; ++ks2) {
                    const int kcA = ks2 * 4 + hi;
                    f16x8 afrag = As[kcA * 128 + (arow ^ kcA)];
                    const int ks = half * 4 + ks2;
                    acc[rt][0] = __builtin_amdgcn_mfma_f32_16x16x32_f16(afrag, bf[ks][0], acc[rt][0], 0, 0, 0);
                    acc[rt][1] = __builtin_amdgcn_mfma_f32_16x16x32_f16(afrag, bf[ks][1], acc[rt][1], 0, 0, 0);
                }
            }
            __syncthreads();
        }

        #pragma unroll
        for (int rt = 0; rt < 4; ++rt)
            #pragma unroll
            for (int cti = 0; cti < 2; ++cti) {
                const int cio = cti * 16 + l15;
                #pragma unroll
                for (int r = 0; r < 4; ++r) {
                    int grow = brow + rh * 64 + rt * 16 + hi * 4 + r;
                    if (grow < Nrows)
                        tmp[((size_t)cls * Nrows + grow) * 32 + cio] = __float2half((float)acc[rt][cti][r]);
                }
            }
    }
}

// ---- rowsort: two-pass counting sort by rowlocal; compact 4B records -----
// sorted record: halfbits(val)<<17 | col   (val>=0 -> 15 bits)
__global__ __launch_bounds__(1024) void rowsort_kernel(const int* __restrict__ bstartP,
                                                       const int* __restrict__ bheadLine,
                                                       const int* __restrict__ bstartD,
                                                       const int2* __restrict__ src,
                                                       unsigned* __restrict__ dst,
                                                       int* __restrict__ starts,
                                                       int N, int NB) {
    __shared__ int lcnt[RB];   // 1024 bins
    __shared__ int sd[RB];
    int b = blockIdx.x;
    int c = b / NB, rb = b - c * NB;
    int t = threadIdx.x;
    int s = bstartP[b];
    int nspan = bheadLine[b] * 8 - s;
    int dbase = bstartD[b];

    lcnt[t] = 0;
    __syncthreads();
    for (int i = t; i < nspan; i += 1024) {
        unsigned u = (unsigned)src[s + i].x;
        if ((u & 0x1FFFFu) != 0x1FFFFu)
            atomicAdd(&lcnt[(u >> 17) & (RB - 1)], 1);
    }
    __syncthreads();
    int v = lcnt[t];
    sd[t] = v; __syncthreads();
    for (int off = 1; off < 1024; off <<= 1) {
        int add = (t >= off) ? sd[t - off] : 0;
        __syncthreads();
        sd[t] += add;
        __syncthreads();
    }
    int excl = sd[t] - v;
    int grow = (rb << RB_LOG) + t;
    if (grow < N) starts[c * N + grow] = dbase + excl;
    __syncthreads();
    lcnt[t] = excl;
    __syncthreads();
    for (int i = t; i < nspan; i += 1024) {
        int2 rec = src[s + i];
        unsigned u = (unsigned)rec.x;
        if ((u & 0x1FFFFu) != 0x1FFFFu) {
            int rl  = (u >> 17) & (RB - 1);
            int pos = atomicAdd(&lcnt[rl], 1);
            __half h = __float2half(__int_as_float(rec.y));
            unsigned hb = (unsigned)*reinterpret_cast<unsigned short*>(&h);
            dst[dbase + pos] = (hb << 17) | (u & 0x1FFFFu);
        }
    }
}

// ---- pull: 8-lane group per (class,row); uint2 (4xfp16) gather; ReLU -----
__global__ __launch_bounds__(256) void pull2_kernel(const int* __restrict__ starts,
                                                    const unsigned* __restrict__ arena,
                                                    const uint2* __restrict__ tmp4,
                                                    float* __restrict__ out,
                                                    int N, int M) {
    int p = blockIdx.x * 32 + (threadIdx.x >> 3);
    if (p >= M) return;
    const int lf = threadIdx.x & 7;   // feature quad: [lf*4, lf*4+4)
    int c   = p / N;
    int row = p - c * N;
    int s = starts[p];
    int n = starts[p + 1] - s;
    const uint2* tc = tmp4 + (size_t)c * N * 8 + lf;   // row stride 8 uint2

    float4 acc = make_float4(0.f, 0.f, 0.f, 0.f);
    int base = 0;
    for (; base + 16 <= n; base += 16) {
        unsigned r[16];
        #pragma unroll
        for (int j = 0; j < 16; ++j) r[j] = arena[s + base + j];
        #pragma unroll
        for (int j = 0; j < 16; ++j) {
            unsigned short hb = (unsigned short)(r[j] >> 17);
            float v = __half2float(*reinterpret_cast<__half*>(&hb));
            uint2 tw = tc[(size_t)(r[j] & 0x1FFFFu) * 8];
            float2 t0 = __half22float2(*reinterpret_cast<__half2*>(&tw.x));
            float2 t1 = __half22float2(*reinterpret_cast<__half2*>(&tw.y));
            acc.x = fmaf(v, t0.x, acc.x);
            acc.y = fmaf(v, t0.y, acc.y);
            acc.z = fmaf(v, t1.x, acc.z);
            acc.w = fmaf(v, t1.y, acc.w);
        }
    }
    if (base + 8 <= n) {
        unsigned r[8];
        #pragma unroll
        for (int j = 0; j < 8; ++j) r[j] = arena[s + base + j];
        #pragma unroll
        for (int j = 0; j < 8; ++j) {
            unsigned short hb = (unsigned short)(r[j] >> 17);
            float v = __half2float(*reinterpret_cast<__half*>(&hb));
            uint2 tw = tc[(size_t)(r[j] & 0x1FFFFu) * 8];
            float2 t0 = __half22float2(*reinterpret_cast<__half2*>(&tw.x));
            float2 t1 = __half22float2(*reinterpret_cast<__half2*>(&tw.y));
            acc.x = fmaf(v, t0.x, acc.x);
            acc.y = fmaf(v, t0.y, acc.y);
            acc.z = fmaf(v, t1.x, acc.z);
            acc.w = fmaf(v, t1.y, acc.w);
        }
        base += 8;
    }
    for (; base < n; ++base) {
        unsigned u = arena[s + base];
        unsigned short hb = (unsigned short)(u >> 17);
        float v = __half2float(*reinterpret_cast<__half*>(&hb));
        uint2 tw = tc[(size_t)(u & 0x1FFFFu) * 8];
        float2 t0 = __half22float2(*reinterpret_cast<__half2*>(&tw.x));
        float2 t1 = __half22float2(*reinterpret_cast<__half2*>(&tw.y));
        acc.x = fmaf(v, t0.x, acc.x);
        acc.y = fmaf(v, t0.y, acc.y);
        acc.z = fmaf(v, t1.x, acc.z);
        acc.w = fmaf(v, t1.y, acc.w);
    }
    *reinterpret_cast<float4*>(&out[(size_t)row * D_OUT + c * D_C + 4 * lf]) =
        make_float4(fmaxf(acc.x, 0.f), fmaxf(acc.y, 0.f),
                    fmaxf(acc.z, 0.f), fmaxf(acc.w, 0.f));
}

// ---- fallback: atomic push + relu ----------------------------------------
__global__ __launch_bounds__(256) void scatter_kernel(const int* __restrict__ rows,
                                                      const int* __restrict__ cols,
                                                      const float* __restrict__ vals,
                                                      const __half* __restrict__ tmp,
                                                      float* __restrict__ out,
                                                      long long totalEdges, int E, int N) {
    long long gid = (long long)blockIdx.x * 8 + (threadIdx.x >> 5);
    if (gid >= totalEdges) return;
    const int lane = threadIdx.x & 31;
    const long long e1 = E, e2 = 2LL * E, e3 = 3LL * E;
    int c = (gid >= e3) ? 3 : (gid >= e2) ? 2 : (gid >= e1) ? 1 : 0;
    const float tv = __half2float(tmp[((size_t)c * N + cols[gid]) * 32 + lane]);
    atomicAdd(&out[(size_t)rows[gid] * D_OUT + c * D_C + lane], tv * vals[gid]);
}

__global__ void relu_kernel(float* __restrict__ out, int n4) {
    int i = blockIdx.x * blockDim.x + threadIdx.x;
    if (i < n4) {
        float4 v = reinterpret_cast<float4*>(out)[i];
        v.x = fmaxf(v.x, 0.f); v.y = fmaxf(v.y, 0.f);
        v.z = fmaxf(v.z, 0.f); v.w = fmaxf(v.w, 0.f);
        reinterpret_cast<float4*>(out)[i] = v;
    }
}

extern "C" void kernel_launch(void* const* d_in, const int* in_sizes, int n_in,
                              void* d_out, int out_size, void* d_ws, size_t ws_size,
                              hipStream_t stream) {
    const float* x    = (const float*)d_in[0];
    const float* W    = (const float*)d_in[1];
    const int*   rows = (const int*)d_in[2];
    const int*   cols = (const int*)d_in[3];
    const float* vals = (const float*)d_in[4];
    float* out = (float*)d_out;

    const int N  = in_sizes[0] / D_IN;      // 100000
    const int CE = in_sizes[2];             // 6,400,000
    const int E  = CE / NUM_C;
    const int NB = (N + RB - 1) >> RB_LOG;  // 98
    const int MB = NUM_C * NB;              // 392
    const int M  = NUM_C * N;               // 400,000

    const int partBlocks = (CE + PART_E - 1) / PART_E;   // 391
    const int gemmBlocks = (N + 127) / 128;              // 782
    const int slackLines = (7 * partBlocks + 7) / 8 + 1;
    const long long capRecs = (long long)((CE + 7) & ~7) + (long long)MB * slackLines * 8 + (long long)MB * 8;

    // workspace layout
    size_t off = 0;
    __half* tmp  = (__half*)((char*)d_ws + off); off += (size_t)N * D_OUT * 2;
    off = (off + 15) & ~(size_t)15;
    __half* Wt   = (__half*)((char*)d_ws + off); off += (size_t)D_IN * D_OUT * 2;
    int* bcnt    = (int*)((char*)d_ws + off);   off += (size_t)MB * 4;
    int* bstartP = (int*)((char*)d_ws + off);   off += (size_t)MB * 4;
    int* bheadL  = (int*)((char*)d_ws + off);   off += (size_t)MB * 4;
    int* bstartD = (int*)((char*)d_ws + off);   off += (size_t)MB * 4;
    int* starts  = (int*)((char*)d_ws + off);   off += (size_t)(M + 1) * 4;
    off = (off + 63) & ~(size_t)63;             // line-align arena
    int2* arena  = (int2*)((char*)d_ws + off);  off += (size_t)capRecs * 8;
    unsigned* sorted = (unsigned*)((char*)d_ws + off); off += (size_t)CE * 4;
    const bool ok = (off <= ws_size) && (MB <= MB_MAX) && (MB <= 512);

    wcvt_kernel<<<(D_IN * D_OUT + 255) / 256, 256, 0, stream>>>(W, Wt);

    if (ok) {
        hipMemsetAsync(bcnt, 0, (size_t)MB * 4, stream);
        const int histBlocks = ((CE >> 2) + 4095) / 4096;
        bucket_hist_kernel<<<histBlocks, 256, 0, stream>>>(rows, bcnt, CE, E, NB, MB);
        bucket_scan_kernel<<<1, 512, 0, stream>>>(bcnt, bstartP, bheadL, bstartD, starts, MB, M, slackLines);
        part_gemm_kernel<<<partBlocks + gemmBlocks, 512, 0, stream>>>(
            rows, cols, vals, bheadL, arena, CE, E, NB, MB, partBlocks, x, Wt, tmp, N);
        rowsort_kernel<<<MB, 1024, 0, stream>>>(bstartP, bheadL, bstartD, arena, sorted, starts, N, NB);
        const int pullBlocks = (M + 31) / 32;
        pull2_kernel<<<pullBlocks, 256, 0, stream>>>(starts, sorted,
                                                     reinterpret_cast<const uint2*>(tmp), out, N, M);
    } else {
        // pure-gemm launch (partBlocks=0 -> gemm idx = blockIdx), then atomic fallback
        part_gemm_kernel<<<gemmBlocks, 512, 0, stream>>>(
            rows, cols, vals, bheadL, arena, CE, E, NB, MB, 0, x, Wt, tmp, N);
        hipMemsetAsync(d_out, 0, (size_t)out_size * sizeof(float), stream);
        const int scatterBlocks = (CE + 7) / 8;
        scatter_kernel<<<scatterBlocks, 256, 0, stream>>>(rows, cols, vals, tmp, out, (long long)CE, E, N);
        const int n4 = out_size / 4;
        relu_kernel<<<(n4 + 255) / 256, 256, 0, stream>>>(out, n4);
    }
}

// Round 18
// 267.248 us; speedup vs baseline: 1.1635x; 1.1042x over previous
//
#include <hip/hip_runtime.h>
#include <hip/hip_bf16.h>
#include <hip/hip_fp16.h>

// Problem constants: N=100000, D_IN=256, C=4, D_C=32, E=1.6e6
#define D_IN 256
#define D_OUT 128   // C * D_C
#define D_C 32
#define NUM_C 4
#define RB_LOG 10
#define RB 1024         // rows per bucket
#define MB_MAX 400      // bucket-array capacity (NUM_C * ceil(N/RB) = 392)
#define RSTASH 20       // rowsort record stash: 20*1024 = 20480 >= max span (~19k)

typedef _Float16 f16x8 __attribute__((ext_vector_type(8)));
typedef float    f32x4 __attribute__((ext_vector_type(4)));

// ---- W convert+transpose: W[256][128] fp32 -> Wt[128][256] fp16 ----------
__global__ void wcvt_kernel(const float* __restrict__ W, __half* __restrict__ Wt) {
    int t = blockIdx.x * 256 + threadIdx.x;   // 0 .. 32767
    if (t >= D_IN * D_OUT) return;
    int col = t >> 8;     // 0..127
    int k   = t & 255;    // 0..255
    Wt[col * D_IN + k] = __float2half(W[k * D_OUT + col]);
}

// ---- shared gemm tile (128 rows, 8 waves, 64KB LDS, full K) --------------
__device__ __forceinline__ void gemm_tile(const float* __restrict__ x,
                                          const __half* __restrict__ Wt,
                                          __half* __restrict__ tmp,
                                          int Nrows, int gidx, char* smem, int t) {
    f16x8* As = (f16x8*)smem;   // 128 rows x 32 kc, swizzled
    const int brow = gidx * 128;
    const int w   = t >> 6;      // wave 0..7
    const int cls = w & 3;       // class
    const int rh  = w >> 2;      // row half: 0..1
    const int l   = t & 63;
    const int l15 = l & 15;
    const int hi  = l >> 4;      // 0..3

    // preload this wave's 16 B-fragments (class cls)
    f16x8 bf[8][2];
    #pragma unroll
    for (int ks = 0; ks < 8; ++ks)
        #pragma unroll
        for (int cti = 0; cti < 2; ++cti)
            bf[ks][cti] = *reinterpret_cast<const f16x8*>(
                Wt + (size_t)((cls * 2 + cti) * 16 + l15) * D_IN + ks * 32 + hi * 8);

    // stage 128-row x-tile -> fp16 LDS
    #pragma unroll
    for (int i = 0; i < 8; ++i) {
        int ci  = i * 512 + t;     // 0..4095
        int row = ci >> 5;         // 0..127
        int kc  = ci & 31;
        int grow = brow + row;
        float4 a0 = make_float4(0.f, 0.f, 0.f, 0.f);
        float4 a1 = make_float4(0.f, 0.f, 0.f, 0.f);
        if (grow < Nrows) {
            const float* src = x + (size_t)grow * D_IN + kc * 8;
            a0 = *reinterpret_cast<const float4*>(src);
            a1 = *reinterpret_cast<const float4*>(src + 4);
        }
        f16x8 hh;
        hh[0] = (_Float16)a0.x; hh[1] = (_Float16)a0.y;
        hh[2] = (_Float16)a0.z; hh[3] = (_Float16)a0.w;
        hh[4] = (_Float16)a1.x; hh[5] = (_Float16)a1.y;
        hh[6] = (_Float16)a1.z; hh[7] = (_Float16)a1.w;
        As[kc * 128 + (row ^ kc)] = hh;
    }
    __syncthreads();

    f32x4 acc[4][2] = {};
    #pragma unroll
    for (int rt = 0; rt < 4; ++rt) {
        const int arow = rh * 64 + rt * 16 + l15;
        #pragma unroll
        for (int ks = 0; ks < 8; ++ks) {
            const int kcA = ks * 4 + hi;
            f16x8 afrag = As[kcA * 128 + (arow ^ kcA)];
            acc[rt][0] = __builtin_amdgcn_mfma_f32_16x16x32_f16(afrag, bf[ks][0], acc[rt][0], 0, 0, 0);
            acc[rt][1] = __builtin_amdgcn_mfma_f32_16x16x32_f16(afrag, bf[ks][1], acc[rt][1], 0, 0, 0);
        }
    }

    #pragma unroll
    for (int rt = 0; rt < 4; ++rt)
        #pragma unroll
        for (int cti = 0; cti < 2; ++cti) {
            const int cio = cti * 16 + l15;
            #pragma unroll
            for (int r = 0; r < 4; ++r) {
                int grow = brow + rh * 64 + rt * 16 + hi * 4 + r;
                if (grow < Nrows)
                    tmp[((size_t)cls * Nrows + grow) * 32 + cio] = __float2half((float)acc[rt][cti][r]);
            }
        }
}

// ---- fused: bucket-hist blocks + first G1 gemm tiles ---------------------
__global__ __launch_bounds__(512) void hist_gemm_kernel(const int* __restrict__ rows,
                                                        int* __restrict__ bcnt,
                                                        int CE, int E, int NB, int MB,
                                                        int histBlocks, int G1,
                                                        const float* __restrict__ x,
                                                        const __half* __restrict__ Wt,
                                                        __half* __restrict__ tmp,
                                                        int Nrows) {
    __shared__ __align__(16) char smem[65536];
    const int t = threadIdx.x;
    const int bid = blockIdx.x;

    if (bid < histBlocks) {
        int* h = (int*)smem;
        for (int i = t; i < MB; i += 512) h[i] = 0;
        __syncthreads();
        const int CE4 = CE >> 2;
        const int4* rows4 = reinterpret_cast<const int4*>(rows);
        int base4 = bid * 4096;
        #pragma unroll 4
        for (int i = 0; i < 8; ++i) {
            int i4 = base4 + t + i * 512;
            if (i4 < CE4) {
                int e0 = i4 << 2;
                int c = (e0 >= 3 * E) ? 3 : (e0 >= 2 * E) ? 2 : (e0 >= E) ? 1 : 0;
                int4 rv = rows4[i4];
                atomicAdd(&h[c * NB + (rv.x >> RB_LOG)], 1);
                atomicAdd(&h[c * NB + (rv.y >> RB_LOG)], 1);
                atomicAdd(&h[c * NB + (rv.z >> RB_LOG)], 1);
                atomicAdd(&h[c * NB + (rv.w >> RB_LOG)], 1);
            }
        }
        if (bid == 0 && t < (CE & 3)) {
            int e = (CE4 << 2) + t;
            int c = (e >= 3 * E) ? 3 : (e >= 2 * E) ? 2 : (e >= E) ? 1 : 0;
            atomicAdd(&h[c * NB + (rows[e] >> RB_LOG)], 1);
        }
        __syncthreads();
        for (int i = t; i < MB; i += 512)
            if (h[i]) atomicAdd(&bcnt[i], h[i]);
    } else {
        int gidx = bid - histBlocks;
        if (gidx < G1) gemm_tile(x, Wt, tmp, Nrows, gidx, smem, t);
    }
}

// ---- scan: padded (line-aligned) + dense offsets -------------------------
__global__ __launch_bounds__(512) void bucket_scan_kernel(const int* __restrict__ bcnt,
                                                          int* __restrict__ bstartP,
                                                          int* __restrict__ bheadLine,
                                                          int* __restrict__ bstartD,
                                                          int* __restrict__ starts,
                                                          int MB, int M, int slackLines) {
    __shared__ int sd[512];
    int t = threadIdx.x;
    int v = (t < MB) ? bcnt[t] : 0;
    int capL = ((v + 7) >> 3) + slackLines;
    sd[t] = capL; __syncthreads();
    for (int off = 1; off < 512; off <<= 1) {
        int add = (t >= off) ? sd[t - off] : 0;
        __syncthreads();
        sd[t] += add;
        __syncthreads();
    }
    int exclL = sd[t] - capL;
    if (t < MB) { bstartP[t] = exclL * 8; bheadLine[t] = exclL; }
    __syncthreads();
    sd[t] = v; __syncthreads();
    for (int off = 1; off < 512; off <<= 1) {
        int add = (t >= off) ? sd[t - off] : 0;
        __syncthreads();
        sd[t] += add;
        __syncthreads();
    }
    int exclD = sd[t] - v;
    if (t < MB) bstartD[t] = exclD;
    if (t == 511) starts[M] = sd[511];   // sentinel = total edges
}

// ---- fused: partition (8192 edges/blk, two-pass) + remaining gemm tiles --
__global__ __launch_bounds__(512) void part_gemm_kernel(const int* __restrict__ rows,
                                                        const int* __restrict__ cols,
                                                        const float* __restrict__ vals,
                                                        int* __restrict__ bheadLine,
                                                        int2* __restrict__ arena,
                                                        int CE, int E, int NB, int MB,
                                                        int partBlocks, int G1, int gemmBlocks,
                                                        const float* __restrict__ x,
                                                        const __half* __restrict__ Wt,
                                                        __half* __restrict__ tmp,
                                                        int Nrows) {
    __shared__ __align__(16) char smem[65536];   // union: As (64KB) | lcnt+lbase
    const int t = threadIdx.x;

    if (blockIdx.x < partBlocks) {
        int* lcnt  = (int*)smem;
        int* lbase = lcnt + MB_MAX;     // absolute RECORD base for this block's run
        for (int i = t; i < MB; i += 512) lcnt[i] = 0;
        __syncthreads();
        const int base = blockIdx.x * 8192;
        const int end  = min(base + 8192, CE);

        // pass 1: count (int4 loads, plain atomics)
        {
            int nvec4 = (end - base) >> 2;
            const int4* rows4 = reinterpret_cast<const int4*>(rows + base);
            #pragma unroll 4
            for (int i = 0; i < 4; ++i) {
                int i4 = t + i * 512;
                if (i4 < nvec4) {
                    int e0 = base + (i4 << 2);
                    int c = (e0 >= 3 * E) ? 3 : (e0 >= 2 * E) ? 2 : (e0 >= E) ? 1 : 0;
                    int4 rv = rows4[i4];
                    atomicAdd(&lcnt[c * NB + (rv.x >> RB_LOG)], 1);
                    atomicAdd(&lcnt[c * NB + (rv.y >> RB_LOG)], 1);
                    atomicAdd(&lcnt[c * NB + (rv.z >> RB_LOG)], 1);
                    atomicAdd(&lcnt[c * NB + (rv.w >> RB_LOG)], 1);
                }
            }
            int e = base + (((end - base) >> 2) << 2) + t;
            if (e < end) {
                int c = (e >= 3 * E) ? 3 : (e >= 2 * E) ? 2 : (e >= E) ? 1 : 0;
                atomicAdd(&lcnt[c * NB + (rows[e] >> RB_LOG)], 1);
            }
        }
        __syncthreads();

        // reserve line-aligned runs
        for (int b = t; b < MB; b += 512) {
            int n = lcnt[b];
            lbase[b] = n ? atomicAdd(&bheadLine[b], (n + 7) >> 3) * 8 : 0;
        }
        __syncthreads();
        for (int i = t; i < MB; i += 512) lcnt[i] = 0;   // reuse as rank counters
        __syncthreads();

        // pass 2: rank + write
        for (int i = 0; i < 16; ++i) {
            int e = base + t + i * 512;
            if (e < end) {
                int c = (e >= 3 * E) ? 3 : (e >= 2 * E) ? 2 : (e >= E) ? 1 : 0;
                int r = rows[e];
                int b = c * NB + (r >> RB_LOG);
                int rank = atomicAdd(&lcnt[b], 1);
                arena[lbase[b] + rank] = make_int2(cols[e] | ((r & (RB - 1)) << 17),
                                                   __float_as_int(vals[e]));
            }
        }
        __syncthreads();

        // pad fill so every reserved line is fully written
        for (int b = t; b < MB; b += 512) {
            int n = lcnt[b];
            if (n) {
                int endp = ((n + 7) >> 3) * 8;
                for (int s2 = n; s2 < endp; ++s2)
                    arena[lbase[b] + s2] = make_int2(-1, 0);
            }
        }
    } else {
        int gidx = G1 + (blockIdx.x - partBlocks);
        if (gidx < gemmBlocks) gemm_tile(x, Wt, tmp, Nrows, gidx, smem, t);
    }
}

// ---- rowsort: single-read stash counting sort; compact 4B records --------
// sorted record: halfbits(val)<<17 | col   (val>=0 -> 15 bits)
__global__ __launch_bounds__(1024) void rowsort_kernel(const int* __restrict__ bstartP,
                                                       const int* __restrict__ bheadLine,
                                                       const int* __restrict__ bstartD,
                                                       const int2* __restrict__ src,
                                                       unsigned* __restrict__ dst,
                                                       int* __restrict__ starts,
                                                       int N, int NB) {
    __shared__ int lcnt[RB];   // 1024 bins
    __shared__ int sd[RB];
    int b = blockIdx.x;
    int c = b / NB, rb = b - c * NB;
    int t = threadIdx.x;
    int s = bstartP[b];
    int nspan = bheadLine[b] * 8 - s;
    int dbase = bstartD[b];

    int2 st[RSTASH];
    lcnt[t] = 0;
    __syncthreads();
    #pragma unroll
    for (int k = 0; k < RSTASH; ++k) {
        int i = t + k * 1024;
        if (i < nspan) {
            int2 rec = src[s + i];
            st[k] = rec;
            unsigned u = (unsigned)rec.x;
            if ((u & 0x1FFFFu) != 0x1FFFFu)
                atomicAdd(&lcnt[(u >> 17) & (RB - 1)], 1);
        }
    }
    for (int i = t + RSTASH * 1024; i < nspan; i += 1024) {
        unsigned u = (unsigned)src[s + i].x;
        if ((u & 0x1FFFFu) != 0x1FFFFu)
            atomicAdd(&lcnt[(u >> 17) & (RB - 1)], 1);
    }
    __syncthreads();
    int v = lcnt[t];
    sd[t] = v; __syncthreads();
    for (int off = 1; off < 1024; off <<= 1) {
        int add = (t >= off) ? sd[t - off] : 0;
        __syncthreads();
        sd[t] += add;
        __syncthreads();
    }
    int excl = sd[t] - v;
    int grow = (rb << RB_LOG) + t;
    if (grow < N) starts[c * N + grow] = dbase + excl;
    __syncthreads();
    lcnt[t] = excl;
    __syncthreads();
    #pragma unroll
    for (int k = 0; k < RSTASH; ++k) {
        int i = t + k * 1024;
        if (i < nspan) {
            int2 rec = st[k];
            unsigned u = (unsigned)rec.x;
            if ((u & 0x1FFFFu) != 0x1FFFFu) {
                int rl  = (u >> 17) & (RB - 1);
                int pos = atomicAdd(&lcnt[rl], 1);
                __half h = __float2half(__int_as_float(rec.y));
                unsigned hb = (unsigned)*reinterpret_cast<unsigned short*>(&h);
                dst[dbase + pos] = (hb << 17) | (u & 0x1FFFFu);
            }
        }
    }
    for (int i = t + RSTASH * 1024; i < nspan; i += 1024) {
        int2 rec = src[s + i];
        unsigned u = (unsigned)rec.x;
        if ((u & 0x1FFFFu) != 0x1FFFFu) {
            int rl  = (u >> 17) & (RB - 1);
            int pos = atomicAdd(&lcnt[rl], 1);
            __half h = __float2half(__int_as_float(rec.y));
            unsigned hb = (unsigned)*reinterpret_cast<unsigned short*>(&h);
            dst[dbase + pos] = (hb << 17) | (u & 0x1FFFFu);
        }
    }
}

// ---- pull: 8-lane group per (class,row); uint2 (4xfp16) gather; ReLU -----
__global__ __launch_bounds__(256) void pull2_kernel(const int* __restrict__ starts,
                                                    const unsigned* __restrict__ arena,
                                                    const uint2* __restrict__ tmp4,
                                                    float* __restrict__ out,
                                                    int N, int M) {
    int p = blockIdx.x * 32 + (threadIdx.x >> 3);
    if (p >= M) return;
    const int lf = threadIdx.x & 7;   // feature quad: [lf*4, lf*4+4)
    int c   = p / N;
    int row = p - c * N;
    int s = starts[p];
    int n = starts[p + 1] - s;
    const uint2* tc = tmp4 + (size_t)c * N * 8 + lf;   // row stride 8 uint2

    float4 acc = make_float4(0.f, 0.f, 0.f, 0.f);
    int base = 0;
    for (; base + 16 <= n; base += 16) {
        unsigned r[16];
        #pragma unroll
        for (int j = 0; j < 16; ++j) r[j] = arena[s + base + j];
        #pragma unroll
        for (int j = 0; j < 16; ++j) {
            unsigned short hb = (unsigned short)(r[j] >> 17);
            float v = __half2float(*reinterpret_cast<__half*>(&hb));
            uint2 tw = tc[(size_t)(r[j] & 0x1FFFFu) * 8];
            float2 t0 = __half22float2(*reinterpret_cast<__half2*>(&tw.x));
            float2 t1 = __half22float2(*reinterpret_cast<__half2*>(&tw.y));
            acc.x = fmaf(v, t0.x, acc.x);
            acc.y = fmaf(v, t0.y, acc.y);
            acc.z = fmaf(v, t1.x, acc.z);
            acc.w = fmaf(v, t1.y, acc.w);
        }
    }
    if (base + 8 <= n) {
        unsigned r[8];
        #pragma unroll
        for (int j = 0; j < 8; ++j) r[j] = arena[s + base + j];
        #pragma unroll
        for (int j = 0; j < 8; ++j) {
            unsigned short hb = (unsigned short)(r[j] >> 17);
            float v = __half2float(*reinterpret_cast<__half*>(&hb));
            uint2 tw = tc[(size_t)(r[j] & 0x1FFFFu) * 8];
            float2 t0 = __half22float2(*reinterpret_cast<__half2*>(&tw.x));
            float2 t1 = __half22float2(*reinterpret_cast<__half2*>(&tw.y));
            acc.x = fmaf(v, t0.x, acc.x);
            acc.y = fmaf(v, t0.y, acc.y);
            acc.z = fmaf(v, t1.x, acc.z);
            acc.w = fmaf(v, t1.y, acc.w);
        }
        base += 8;
    }
    for (; base < n; ++base) {
        unsigned u = arena[s + base];
        unsigned short hb = (unsigned short)(u >> 17);
        float v = __half2float(*reinterpret_cast<__half*>(&hb));
        uint2 tw = tc[(size_t)(u & 0x1FFFFu) * 8];
        float2 t0 = __half22float2(*reinterpret_cast<__half2*>(&tw.x));
        float2 t1 = __half22float2(*reinterpret_cast<__half2*>(&tw.y));
        acc.x = fmaf(v, t0.x, acc.x);
        acc.y = fmaf(v, t0.y, acc.y);
        acc.z = fmaf(v, t1.x, acc.z);
        acc.w = fmaf(v, t1.y, acc.w);
    }
    *reinterpret_cast<float4*>(&out[(size_t)row * D_OUT + c * D_C + 4 * lf]) =
        make_float4(fmaxf(acc.x, 0.f), fmaxf(acc.y, 0.f),
                    fmaxf(acc.z, 0.f), fmaxf(acc.w, 0.f));
}

// ---- fallback: atomic push + relu ----------------------------------------
__global__ __launch_bounds__(256) void scatter_kernel(const int* __restrict__ rows,
                                                      const int* __restrict__ cols,
                                                      const float* __restrict__ vals,
                                                      const __half* __restrict__ tmp,
                                                      float* __restrict__ out,
                                                      long long totalEdges, int E, int N) {
    long long gid = (long long)blockIdx.x * 8 + (threadIdx.x >> 5);
    if (gid >= totalEdges) return;
    const int lane = threadIdx.x & 31;
    const long long e1 = E, e2 = 2LL * E, e3 = 3LL * E;
    int c = (gid >= e3) ? 3 : (gid >= e2) ? 2 : (gid >= e1) ? 1 : 0;
    const float tv = __half2float(tmp[((size_t)c * N + cols[gid]) * 32 + lane]);
    atomicAdd(&out[(size_t)rows[gid] * D_OUT + c * D_C + lane], tv * vals[gid]);
}

__global__ void relu_kernel(float* __restrict__ out, int n4) {
    int i = blockIdx.x * blockDim.x + threadIdx.x;
    if (i < n4) {
        float4 v = reinterpret_cast<float4*>(out)[i];
        v.x = fmaxf(v.x, 0.f); v.y = fmaxf(v.y, 0.f);
        v.z = fmaxf(v.z, 0.f); v.w = fmaxf(v.w, 0.f);
        reinterpret_cast<float4*>(out)[i] = v;
    }
}

extern "C" void kernel_launch(void* const* d_in, const int* in_sizes, int n_in,
                              void* d_out, int out_size, void* d_ws, size_t ws_size,
                              hipStream_t stream) {
    const float* x    = (const float*)d_in[0];
    const float* W    = (const float*)d_in[1];
    const int*   rows = (const int*)d_in[2];
    const int*   cols = (const int*)d_in[3];
    const float* vals = (const float*)d_in[4];
    float* out = (float*)d_out;

    const int N  = in_sizes[0] / D_IN;      // 100000
    const int CE = in_sizes[2];             // 6,400,000
    const int E  = CE / NUM_C;
    const int NB = (N + RB - 1) >> RB_LOG;  // 98
    const int MB = NUM_C * NB;              // 392
    const int M  = NUM_C * N;               // 400,000

    const int partBlocks = (CE + 8191) / 8192;          // 782
    const int gemmBlocks = (N + 127) / 128;             // 782
    const int G1 = min(256, gemmBlocks);                // gemm tiles fused with hist
    const int slackLines = (7 * partBlocks + 7) / 8 + 1;
    const long long capRecs = (long long)((CE + 7) & ~7) + (long long)MB * slackLines * 8 + (long long)MB * 8;

    // workspace layout
    size_t off = 0;
    __half* tmp  = (__half*)((char*)d_ws + off); off += (size_t)N * D_OUT * 2;
    off = (off + 15) & ~(size_t)15;
    __half* Wt   = (__half*)((char*)d_ws + off); off += (size_t)D_IN * D_OUT * 2;
    int* bcnt    = (int*)((char*)d_ws + off);   off += (size_t)MB * 4;
    int* bstartP = (int*)((char*)d_ws + off);   off += (size_t)MB * 4;
    int* bheadL  = (int*)((char*)d_ws + off);   off += (size_t)MB * 4;
    int* bstartD = (int*)((char*)d_ws + off);   off += (size_t)MB * 4;
    int* starts  = (int*)((char*)d_ws + off);   off += (size_t)(M + 1) * 4;
    off = (off + 63) & ~(size_t)63;             // line-align arena
    int2* arena  = (int2*)((char*)d_ws + off);  off += (size_t)capRecs * 8;
    unsigned* sorted = (unsigned*)((char*)d_ws + off); off += (size_t)CE * 4;
    const bool ok = (off <= ws_size) && (MB <= MB_MAX) && (MB <= 512);

    wcvt_kernel<<<(D_IN * D_OUT + 255) / 256, 256, 0, stream>>>(W, Wt);

    const int histBlocks = ((CE >> 2) + 4095) / 4096;   // 391

    if (ok) {
        hipMemsetAsync(bcnt, 0, (size_t)MB * 4, stream);
        hist_gemm_kernel<<<histBlocks + G1, 512, 0, stream>>>(
            rows, bcnt, CE, E, NB, MB, histBlocks, G1, x, Wt, tmp, N);
        bucket_scan_kernel<<<1, 512, 0, stream>>>(bcnt, bstartP, bheadL, bstartD, starts, MB, M, slackLines);
        part_gemm_kernel<<<partBlocks + (gemmBlocks - G1), 512, 0, stream>>>(
            rows, cols, vals, bheadL, arena, CE, E, NB, MB, partBlocks, G1, gemmBlocks, x, Wt, tmp, N);
        rowsort_kernel<<<MB, 1024, 0, stream>>>(bstartP, bheadL, bstartD, arena, sorted, starts, N, NB);
        const int pullBlocks = (M + 31) / 32;
        pull2_kernel<<<pullBlocks, 256, 0, stream>>>(starts, sorted,
                                                     reinterpret_cast<const uint2*>(tmp), out, N, M);
    } else {
        // pure-gemm launch (partBlocks=0, G1=0 -> gemm idx = blockIdx), then atomic fallback
        part_gemm_kernel<<<gemmBlocks, 512, 0, stream>>>(
            rows, cols, vals, bheadL, arena, CE, E, NB, MB, 0, 0, gemmBlocks, x, Wt, tmp, N);
        hipMemsetAsync(d_out, 0, (size_t)out_size * sizeof(float), stream);
        const int scatterBlocks = (CE + 7) / 8;
        scatter_kernel<<<scatterBlocks, 256, 0, stream>>>(rows, cols, vals, tmp, out, (long long)CE, E, N);
        const int n4 = out_size / 4;
        relu_kernel<<<(n4 + 255) / 256, 256, 0, stream>>>(out, n4);
    }
}

// Round 19
// 256.553 us; speedup vs baseline: 1.2120x; 1.0417x over previous
//
#include <hip/hip_runtime.h>
#include <hip/hip_bf16.h>
#include <hip/hip_fp16.h>

// Problem constants: N=100000, D_IN=256, C=4, D_C=32, E=1.6e6
#define D_IN 256
#define D_OUT 128   // C * D_C
#define D_C 32
#define NUM_C 4
#define RB_LOG 10
#define RB 1024         // rows per bucket
#define MB_MAX 400      // bucket-array capacity (NUM_C * ceil(N/RB) = 392)
#define RSTASH 20       // rowsort record stash: 20*1024 = 20480 >= max span (~19k)

typedef _Float16 f16x8 __attribute__((ext_vector_type(8)));
typedef float    f32x4 __attribute__((ext_vector_type(4)));

// ---- W convert+transpose: W[256][128] fp32 -> Wt[128][256] fp16 ----------
__global__ void wcvt_kernel(const float* __restrict__ W, __half* __restrict__ Wt) {
    int t = blockIdx.x * 256 + threadIdx.x;   // 0 .. 32767
    if (t >= D_IN * D_OUT) return;
    int col = t >> 8;     // 0..127
    int k   = t & 255;    // 0..255
    Wt[col * D_IN + k] = __float2half(W[k * D_OUT + col]);
}

// ---- shared gemm tile (128 rows, 8 waves, 64KB LDS, full K) --------------
__device__ __forceinline__ void gemm_tile(const float* __restrict__ x,
                                          const __half* __restrict__ Wt,
                                          __half* __restrict__ tmp,
                                          int Nrows, int gidx, char* smem, int t) {
    f16x8* As = (f16x8*)smem;   // 128 rows x 32 kc, swizzled
    const int brow = gidx * 128;
    const int w   = t >> 6;      // wave 0..7
    const int cls = w & 3;       // class
    const int rh  = w >> 2;      // row half: 0..1
    const int l   = t & 63;
    const int l15 = l & 15;
    const int hi  = l >> 4;      // 0..3

    // preload this wave's 16 B-fragments (class cls)
    f16x8 bf[8][2];
    #pragma unroll
    for (int ks = 0; ks < 8; ++ks)
        #pragma unroll
        for (int cti = 0; cti < 2; ++cti)
            bf[ks][cti] = *reinterpret_cast<const f16x8*>(
                Wt + (size_t)((cls * 2 + cti) * 16 + l15) * D_IN + ks * 32 + hi * 8);

    // stage 128-row x-tile -> fp16 LDS
    #pragma unroll
    for (int i = 0; i < 8; ++i) {
        int ci  = i * 512 + t;     // 0..4095
        int row = ci >> 5;         // 0..127
        int kc  = ci & 31;
        int grow = brow + row;
        float4 a0 = make_float4(0.f, 0.f, 0.f, 0.f);
        float4 a1 = make_float4(0.f, 0.f, 0.f, 0.f);
        if (grow < Nrows) {
            const float* src = x + (size_t)grow * D_IN + kc * 8;
            a0 = *reinterpret_cast<const float4*>(src);
            a1 = *reinterpret_cast<const float4*>(src + 4);
        }
        f16x8 hh;
        hh[0] = (_Float16)a0.x; hh[1] = (_Float16)a0.y;
        hh[2] = (_Float16)a0.z; hh[3] = (_Float16)a0.w;
        hh[4] = (_Float16)a1.x; hh[5] = (_Float16)a1.y;
        hh[6] = (_Float16)a1.z; hh[7] = (_Float16)a1.w;
        As[kc * 128 + (row ^ kc)] = hh;
    }
    __syncthreads();

    f32x4 acc[4][2] = {};
    #pragma unroll
    for (int rt = 0; rt < 4; ++rt) {
        const int arow = rh * 64 + rt * 16 + l15;
        #pragma unroll
        for (int ks = 0; ks < 8; ++ks) {
            const int kcA = ks * 4 + hi;
            f16x8 afrag = As[kcA * 128 + (arow ^ kcA)];
            acc[rt][0] = __builtin_amdgcn_mfma_f32_16x16x32_f16(afrag, bf[ks][0], acc[rt][0], 0, 0, 0);
            acc[rt][1] = __builtin_amdgcn_mfma_f32_16x16x32_f16(afrag, bf[ks][1], acc[rt][1], 0, 0, 0);
        }
    }

    #pragma unroll
    for (int rt = 0; rt < 4; ++rt)
        #pragma unroll
        for (int cti = 0; cti < 2; ++cti) {
            const int cio = cti * 16 + l15;
            #pragma unroll
            for (int r = 0; r < 4; ++r) {
                int grow = brow + rh * 64 + rt * 16 + hi * 4 + r;
                if (grow < Nrows)
                    tmp[((size_t)cls * Nrows + grow) * 32 + cio] = __float2half((float)acc[rt][cti][r]);
            }
        }
}

// ---- fused: bucket-hist blocks + first G1 gemm tiles ---------------------
__global__ __launch_bounds__(512) void hist_gemm_kernel(const int* __restrict__ rows,
                                                        int* __restrict__ bcnt,
                                                        int CE, int E, int NB, int MB,
                                                        int histBlocks, int G1,
                                                        const float* __restrict__ x,
                                                        const __half* __restrict__ Wt,
                                                        __half* __restrict__ tmp,
                                                        int Nrows) {
    __shared__ __align__(16) char smem[65536];
    const int t = threadIdx.x;
    const int bid = blockIdx.x;

    if (bid < histBlocks) {
        int* h = (int*)smem;
        for (int i = t; i < MB; i += 512) h[i] = 0;
        __syncthreads();
        const int CE4 = CE >> 2;
        const int4* rows4 = reinterpret_cast<const int4*>(rows);
        int base4 = bid * 4096;
        #pragma unroll 4
        for (int i = 0; i < 8; ++i) {
            int i4 = base4 + t + i * 512;
            if (i4 < CE4) {
                int e0 = i4 << 2;
                int c = (e0 >= 3 * E) ? 3 : (e0 >= 2 * E) ? 2 : (e0 >= E) ? 1 : 0;
                int4 rv = rows4[i4];
                atomicAdd(&h[c * NB + (rv.x >> RB_LOG)], 1);
                atomicAdd(&h[c * NB + (rv.y >> RB_LOG)], 1);
                atomicAdd(&h[c * NB + (rv.z >> RB_LOG)], 1);
                atomicAdd(&h[c * NB + (rv.w >> RB_LOG)], 1);
            }
        }
        if (bid == 0 && t < (CE & 3)) {
            int e = (CE4 << 2) + t;
            int c = (e >= 3 * E) ? 3 : (e >= 2 * E) ? 2 : (e >= E) ? 1 : 0;
            atomicAdd(&h[c * NB + (rows[e] >> RB_LOG)], 1);
        }
        __syncthreads();
        for (int i = t; i < MB; i += 512)
            if (h[i]) atomicAdd(&bcnt[i], h[i]);
    } else {
        int gidx = bid - histBlocks;
        if (gidx < G1) gemm_tile(x, Wt, tmp, Nrows, gidx, smem, t);
    }
}

// ---- scan: padded (line-aligned) + dense offsets -------------------------
__global__ __launch_bounds__(512) void bucket_scan_kernel(const int* __restrict__ bcnt,
                                                          int* __restrict__ bstartP,
                                                          int* __restrict__ bheadLine,
                                                          int* __restrict__ bstartD,
                                                          int* __restrict__ starts,
                                                          int MB, int M, int slackLines) {
    __shared__ int sd[512];
    int t = threadIdx.x;
    int v = (t < MB) ? bcnt[t] : 0;
    int capL = ((v + 7) >> 3) + slackLines;
    sd[t] = capL; __syncthreads();
    for (int off = 1; off < 512; off <<= 1) {
        int add = (t >= off) ? sd[t - off] : 0;
        __syncthreads();
        sd[t] += add;
        __syncthreads();
    }
    int exclL = sd[t] - capL;
    if (t < MB) { bstartP[t] = exclL * 8; bheadLine[t] = exclL; }
    __syncthreads();
    sd[t] = v; __syncthreads();
    for (int off = 1; off < 512; off <<= 1) {
        int add = (t >= off) ? sd[t - off] : 0;
        __syncthreads();
        sd[t] += add;
        __syncthreads();
    }
    int exclD = sd[t] - v;
    if (t < MB) bstartD[t] = exclD;
    if (t == 511) starts[M] = sd[511];   // sentinel = total edges
}

// ---- fused: partition (chunk edges/blk, two-pass) + remaining gemm tiles -
__global__ __launch_bounds__(512) void part_gemm_kernel(const int* __restrict__ rows,
                                                        const int* __restrict__ cols,
                                                        const float* __restrict__ vals,
                                                        int* __restrict__ bheadLine,
                                                        int2* __restrict__ arena,
                                                        int CE, int E, int NB, int MB,
                                                        int partBlocks, int partChunk,
                                                        int G1, int gemmBlocks,
                                                        const float* __restrict__ x,
                                                        const __half* __restrict__ Wt,
                                                        __half* __restrict__ tmp,
                                                        int Nrows) {
    __shared__ __align__(16) char smem[65536];   // union: As (64KB) | lcnt+lbase
    const int t = threadIdx.x;

    if (blockIdx.x < partBlocks) {
        int* lcnt  = (int*)smem;
        int* lbase = lcnt + MB_MAX;     // absolute RECORD base for this block's run
        for (int i = t; i < MB; i += 512) lcnt[i] = 0;
        __syncthreads();
        const int base = blockIdx.x * partChunk;
        const int end  = min(base + partChunk, CE);

        // pass 1: count (int4 loads, plain atomics)
        {
            int nvec4 = (end - base) >> 2;
            const int4* rows4 = reinterpret_cast<const int4*>(rows + base);
            for (int i4 = t; i4 < nvec4; i4 += 512) {
                int e0 = base + (i4 << 2);
                int c = (e0 >= 3 * E) ? 3 : (e0 >= 2 * E) ? 2 : (e0 >= E) ? 1 : 0;
                int4 rv = rows4[i4];
                atomicAdd(&lcnt[c * NB + (rv.x >> RB_LOG)], 1);
                atomicAdd(&lcnt[c * NB + (rv.y >> RB_LOG)], 1);
                atomicAdd(&lcnt[c * NB + (rv.z >> RB_LOG)], 1);
                atomicAdd(&lcnt[c * NB + (rv.w >> RB_LOG)], 1);
            }
            int e = base + (nvec4 << 2) + t;
            if (e < end) {
                int c = (e >= 3 * E) ? 3 : (e >= 2 * E) ? 2 : (e >= E) ? 1 : 0;
                atomicAdd(&lcnt[c * NB + (rows[e] >> RB_LOG)], 1);
            }
        }
        __syncthreads();

        // reserve line-aligned runs
        for (int b = t; b < MB; b += 512) {
            int n = lcnt[b];
            lbase[b] = n ? atomicAdd(&bheadLine[b], (n + 7) >> 3) * 8 : 0;
        }
        __syncthreads();
        for (int i = t; i < MB; i += 512) lcnt[i] = 0;   // reuse as rank counters
        __syncthreads();

        // pass 2: rank + write
        for (int e = base + t; e < end; e += 512) {
            int c = (e >= 3 * E) ? 3 : (e >= 2 * E) ? 2 : (e >= E) ? 1 : 0;
            int r = rows[e];
            int b = c * NB + (r >> RB_LOG);
            int rank = atomicAdd(&lcnt[b], 1);
            arena[lbase[b] + rank] = make_int2(cols[e] | ((r & (RB - 1)) << 17),
                                               __float_as_int(vals[e]));
        }
        __syncthreads();

        // pad fill so every reserved line is fully written
        for (int b = t; b < MB; b += 512) {
            int n = lcnt[b];
            if (n) {
                int endp = ((n + 7) >> 3) * 8;
                for (int s2 = n; s2 < endp; ++s2)
                    arena[lbase[b] + s2] = make_int2(-1, 0);
            }
        }
    } else {
        int gidx = G1 + (blockIdx.x - partBlocks);
        if (gidx < gemmBlocks) gemm_tile(x, Wt, tmp, Nrows, gidx, smem, t);
    }
}

// ---- rowsort: single-read stash counting sort; compact 4B records --------
// sorted record: halfbits(val)<<17 | col   (val>=0 -> 15 bits)
__global__ __launch_bounds__(1024) void rowsort_kernel(const int* __restrict__ bstartP,
                                                       const int* __restrict__ bheadLine,
                                                       const int* __restrict__ bstartD,
                                                       const int2* __restrict__ src,
                                                       unsigned* __restrict__ dst,
                                                       int* __restrict__ starts,
                                                       int N, int NB) {
    __shared__ int lcnt[RB];   // 1024 bins
    __shared__ int sd[RB];
    int b = blockIdx.x;
    int c = b / NB, rb = b - c * NB;
    int t = threadIdx.x;
    int s = bstartP[b];
    int nspan = bheadLine[b] * 8 - s;
    int dbase = bstartD[b];

    int2 st[RSTASH];
    lcnt[t] = 0;
    __syncthreads();
    #pragma unroll
    for (int k = 0; k < RSTASH; ++k) {
        int i = t + k * 1024;
        if (i < nspan) {
            int2 rec = src[s + i];
            st[k] = rec;
            unsigned u = (unsigned)rec.x;
            if ((u & 0x1FFFFu) != 0x1FFFFu)
                atomicAdd(&lcnt[(u >> 17) & (RB - 1)], 1);
        }
    }
    for (int i = t + RSTASH * 1024; i < nspan; i += 1024) {
        unsigned u = (unsigned)src[s + i].x;
        if ((u & 0x1FFFFu) != 0x1FFFFu)
            atomicAdd(&lcnt[(u >> 17) & (RB - 1)], 1);
    }
    __syncthreads();
    int v = lcnt[t];
    sd[t] = v; __syncthreads();
    for (int off = 1; off < 1024; off <<= 1) {
        int add = (t >= off) ? sd[t - off] : 0;
        __syncthreads();
        sd[t] += add;
        __syncthreads();
    }
    int excl = sd[t] - v;
    int grow = (rb << RB_LOG) + t;
    if (grow < N) starts[c * N + grow] = dbase + excl;
    __syncthreads();
    lcnt[t] = excl;
    __syncthreads();
    #pragma unroll
    for (int k = 0; k < RSTASH; ++k) {
        int i = t + k * 1024;
        if (i < nspan) {
            int2 rec = st[k];
            unsigned u = (unsigned)rec.x;
            if ((u & 0x1FFFFu) != 0x1FFFFu) {
                int rl  = (u >> 17) & (RB - 1);
                int pos = atomicAdd(&lcnt[rl], 1);
                __half h = __float2half(__int_as_float(rec.y));
                unsigned hb = (unsigned)*reinterpret_cast<unsigned short*>(&h);
                dst[dbase + pos] = (hb << 17) | (u & 0x1FFFFu);
            }
        }
    }
    for (int i = t + RSTASH * 1024; i < nspan; i += 1024) {
        int2 rec = src[s + i];
        unsigned u = (unsigned)rec.x;
        if ((u & 0x1FFFFu) != 0x1FFFFu) {
            int rl  = (u >> 17) & (RB - 1);
            int pos = atomicAdd(&lcnt[rl], 1);
            __half h = __float2half(__int_as_float(rec.y));
            unsigned hb = (unsigned)*reinterpret_cast<unsigned short*>(&h);
            dst[dbase + pos] = (hb << 17) | (u & 0x1FFFFu);
        }
    }
}

// ---- pull: 4-lane group per (class,row); uint4 (8xfp16) gather; ReLU -----
__global__ __launch_bounds__(256) void pull2_kernel(const int* __restrict__ starts,
                                                    const unsigned* __restrict__ arena,
                                                    const uint4* __restrict__ tmp8,
                                                    float* __restrict__ out,
                                                    int N, int M) {
    int p = blockIdx.x * 64 + (threadIdx.x >> 2);
    if (p >= M) return;
    const int lf = threadIdx.x & 3;   // feature oct: [lf*8, lf*8+8)
    int c   = p / N;
    int row = p - c * N;
    int s = starts[p];
    int n = starts[p + 1] - s;
    const uint4* tc = tmp8 + (size_t)c * N * 4 + lf;   // row stride 4 uint4

    float acc[8] = {};
    int base = 0;
    for (; base + 16 <= n; base += 16) {
        unsigned r[16];
        #pragma unroll
        for (int j = 0; j < 16; ++j) r[j] = arena[s + base + j];
        #pragma unroll
        for (int j = 0; j < 16; ++j) {
            unsigned short hb = (unsigned short)(r[j] >> 17);
            float v = __half2float(*reinterpret_cast<__half*>(&hb));
            uint4 tw = tc[(size_t)(r[j] & 0x1FFFFu) * 4];
            float2 t0 = __half22float2(*reinterpret_cast<__half2*>(&tw.x));
            float2 t1 = __half22float2(*reinterpret_cast<__half2*>(&tw.y));
            float2 t2 = __half22float2(*reinterpret_cast<__half2*>(&tw.z));
            float2 t3 = __half22float2(*reinterpret_cast<__half2*>(&tw.w));
            acc[0] = fmaf(v, t0.x, acc[0]); acc[1] = fmaf(v, t0.y, acc[1]);
            acc[2] = fmaf(v, t1.x, acc[2]); acc[3] = fmaf(v, t1.y, acc[3]);
            acc[4] = fmaf(v, t2.x, acc[4]); acc[5] = fmaf(v, t2.y, acc[5]);
            acc[6] = fmaf(v, t3.x, acc[6]); acc[7] = fmaf(v, t3.y, acc[7]);
        }
    }
    if (base + 8 <= n) {
        unsigned r[8];
        #pragma unroll
        for (int j = 0; j < 8; ++j) r[j] = arena[s + base + j];
        #pragma unroll
        for (int j = 0; j < 8; ++j) {
            unsigned short hb = (unsigned short)(r[j] >> 17);
            float v = __half2float(*reinterpret_cast<__half*>(&hb));
            uint4 tw = tc[(size_t)(r[j] & 0x1FFFFu) * 4];
            float2 t0 = __half22float2(*reinterpret_cast<__half2*>(&tw.x));
            float2 t1 = __half22float2(*reinterpret_cast<__half2*>(&tw.y));
            float2 t2 = __half22float2(*reinterpret_cast<__half2*>(&tw.z));
            float2 t3 = __half22float2(*reinterpret_cast<__half2*>(&tw.w));
            acc[0] = fmaf(v, t0.x, acc[0]); acc[1] = fmaf(v, t0.y, acc[1]);
            acc[2] = fmaf(v, t1.x, acc[2]); acc[3] = fmaf(v, t1.y, acc[3]);
            acc[4] = fmaf(v, t2.x, acc[4]); acc[5] = fmaf(v, t2.y, acc[5]);
            acc[6] = fmaf(v, t3.x, acc[6]); acc[7] = fmaf(v, t3.y, acc[7]);
        }
        base += 8;
    }
    for (; base < n; ++base) {
        unsigned u = arena[s + base];
        unsigned short hb = (unsigned short)(u >> 17);
        float v = __half2float(*reinterpret_cast<__half*>(&hb));
        uint4 tw = tc[(size_t)(u & 0x1FFFFu) * 4];
        float2 t0 = __half22float2(*reinterpret_cast<__half2*>(&tw.x));
        float2 t1 = __half22float2(*reinterpret_cast<__half2*>(&tw.y));
        float2 t2 = __half22float2(*reinterpret_cast<__half2*>(&tw.z));
        float2 t3 = __half22float2(*reinterpret_cast<__half2*>(&tw.w));
        acc[0] = fmaf(v, t0.x, acc[0]); acc[1] = fmaf(v, t0.y, acc[1]);
        acc[2] = fmaf(v, t1.x, acc[2]); acc[3] = fmaf(v, t1.y, acc[3]);
        acc[4] = fmaf(v, t2.x, acc[4]); acc[5] = fmaf(v, t2.y, acc[5]);
        acc[6] = fmaf(v, t3.x, acc[6]); acc[7] = fmaf(v, t3.y, acc[7]);
    }
    float* o = &out[(size_t)row * D_OUT + c * D_C + 8 * lf];
    *reinterpret_cast<float4*>(o) =
        make_float4(fmaxf(acc[0], 0.f), fmaxf(acc[1], 0.f), fmaxf(acc[2], 0.f), fmaxf(acc[3], 0.f));
    *reinterpret_cast<float4*>(o + 4) =
        make_float4(fmaxf(acc[4], 0.f), fmaxf(acc[5], 0.f), fmaxf(acc[6], 0.f), fmaxf(acc[7], 0.f));
}

// ---- fallback: atomic push + relu ----------------------------------------
__global__ __launch_bounds__(256) void scatter_kernel(const int* __restrict__ rows,
                                                      const int* __restrict__ cols,
                                                      const float* __restrict__ vals,
                                                      const __half* __restrict__ tmp,
                                                      float* __restrict__ out,
                                                      long long totalEdges, int E, int N) {
    long long gid = (long long)blockIdx.x * 8 + (threadIdx.x >> 5);
    if (gid >= totalEdges) return;
    const int lane = threadIdx.x & 31;
    const long long e1 = E, e2 = 2LL * E, e3 = 3LL * E;
    int c = (gid >= e3) ? 3 : (gid >= e2) ? 2 : (gid >= e1) ? 1 : 0;
    const float tv = __half2float(tmp[((size_t)c * N + cols[gid]) * 32 + lane]);
    atomicAdd(&out[(size_t)rows[gid] * D_OUT + c * D_C + lane], tv * vals[gid]);
}

__global__ void relu_kernel(float* __restrict__ out, int n4) {
    int i = blockIdx.x * blockDim.x + threadIdx.x;
    if (i < n4) {
        float4 v = reinterpret_cast<float4*>(out)[i];
        v.x = fmaxf(v.x, 0.f); v.y = fmaxf(v.y, 0.f);
        v.z = fmaxf(v.z, 0.f); v.w = fmaxf(v.w, 0.f);
        reinterpret_cast<float4*>(out)[i] = v;
    }
}

extern "C" void kernel_launch(void* const* d_in, const int* in_sizes, int n_in,
                              void* d_out, int out_size, void* d_ws, size_t ws_size,
                              hipStream_t stream) {
    const float* x    = (const float*)d_in[0];
    const float* W    = (const float*)d_in[1];
    const int*   rows = (const int*)d_in[2];
    const int*   cols = (const int*)d_in[3];
    const float* vals = (const float*)d_in[4];
    float* out = (float*)d_out;

    const int N  = in_sizes[0] / D_IN;      // 100000
    const int CE = in_sizes[2];             // 6,400,000
    const int E  = CE / NUM_C;
    const int NB = (N + RB - 1) >> RB_LOG;  // 98
    const int MB = NUM_C * NB;              // 392
    const int M  = NUM_C * N;               // 400,000

    const int gemmBlocks = (N + 127) / 128;             // 782
    const int G1 = min(391, gemmBlocks);                // gemm tiles fused with hist

    // choose partition chunk: prefer 4096 (more TLP); fall back to 8192 if ws tight
    int partChunk = 4096, partBlocks = 0, slackLines = 0;
    long long capRecs = 0;
    size_t off = 0;
    __half* tmp; __half* Wt; int *bcnt, *bstartP, *bheadL, *bstartD, *starts;
    int2* arena; unsigned* sorted;
    bool ok = false;
    for (int attempt = 0; attempt < 2; ++attempt) {
        partBlocks = (CE + partChunk - 1) / partChunk;
        slackLines = (7 * partBlocks + 7) / 8 + 1;
        capRecs = (long long)((CE + 7) & ~7) + (long long)MB * slackLines * 8 + (long long)MB * 8;
        off = 0;
        tmp  = (__half*)((char*)d_ws + off); off += (size_t)N * D_OUT * 2;
        off = (off + 15) & ~(size_t)15;
        Wt   = (__half*)((char*)d_ws + off); off += (size_t)D_IN * D_OUT * 2;
        bcnt    = (int*)((char*)d_ws + off); off += (size_t)MB * 4;
        bstartP = (int*)((char*)d_ws + off); off += (size_t)MB * 4;
        bheadL  = (int*)((char*)d_ws + off); off += (size_t)MB * 4;
        bstartD = (int*)((char*)d_ws + off); off += (size_t)MB * 4;
        starts  = (int*)((char*)d_ws + off); off += (size_t)(M + 1) * 4;
        off = (off + 63) & ~(size_t)63;
        arena  = (int2*)((char*)d_ws + off); off += (size_t)capRecs * 8;
        sorted = (unsigned*)((char*)d_ws + off); off += (size_t)CE * 4;
        ok = (off <= ws_size) && (MB <= MB_MAX) && (MB <= 512);
        if (ok || attempt == 1) break;
        partChunk = 8192;
    }

    wcvt_kernel<<<(D_IN * D_OUT + 255) / 256, 256, 0, stream>>>(W, Wt);

    const int histBlocks = ((CE >> 2) + 4095) / 4096;   // 391

    if (ok) {
        hipMemsetAsync(bcnt, 0, (size_t)MB * 4, stream);
        hist_gemm_kernel<<<histBlocks + G1, 512, 0, stream>>>(
            rows, bcnt, CE, E, NB, MB, histBlocks, G1, x, Wt, tmp, N);
        bucket_scan_kernel<<<1, 512, 0, stream>>>(bcnt, bstartP, bheadL, bstartD, starts, MB, M, slackLines);
        part_gemm_kernel<<<partBlocks + (gemmBlocks - G1), 512, 0, stream>>>(
            rows, cols, vals, bheadL, arena, CE, E, NB, MB, partBlocks, partChunk, G1, gemmBlocks, x, Wt, tmp, N);
        rowsort_kernel<<<MB, 1024, 0, stream>>>(bstartP, bheadL, bstartD, arena, sorted, starts, N, NB);
        const int pullBlocks = (M + 63) / 64;
        pull2_kernel<<<pullBlocks, 256, 0, stream>>>(starts, sorted,
                                                     reinterpret_cast<const uint4*>(tmp), out, N, M);
    } else {
        // pure-gemm launch (partBlocks=0, G1=0 -> gemm idx = blockIdx), then atomic fallback
        part_gemm_kernel<<<gemmBlocks, 512, 0, stream>>>(
            rows, cols, vals, bheadL, arena, CE, E, NB, MB, 0, 8192, 0, gemmBlocks, x, Wt, tmp, N);
        hipMemsetAsync(d_out, 0, (size_t)out_size * sizeof(float), stream);
        const int scatterBlocks = (CE + 7) / 8;
        scatter_kernel<<<scatterBlocks, 256, 0, stream>>>(rows, cols, vals, tmp, out, (long long)CE, E, N);
        const int n4 = out_size / 4;
        relu_kernel<<<(n4 + 255) / 256, 256, 0, stream>>>(out, n4);
    }
}